// Round 4
// baseline (304.715 us; speedup 1.0000x reference)
//
#include <hip/hip_runtime.h>

#define NNODES 50000
#define NEDGES 1600000
#define NB 196        // buckets = dst>>8  (50000/256 -> 0..195)
#define BCAP 10240    // edges per bucket capacity (mean 8163, +20 sigma)
#define P1B 782       // ceil(NEDGES/2048) == ceil(NNODES/64) == 782

typedef __attribute__((ext_vector_type(8))) short short8;   // 8 x bf16
typedef __attribute__((ext_vector_type(4))) float fp32x4;   // MFMA C/D frag

__device__ __forceinline__ unsigned short f2bf(float f) {   // RNE fp32 -> bf16
    unsigned int u = __float_as_uint(f);
    u += 0x7fffu + ((u >> 16) & 1u);
    return (unsigned short)(u >> 16);
}
__device__ __forceinline__ float bflo(unsigned int p) { return __uint_as_float(p << 16); }
__device__ __forceinline__ float bfhi(unsigned int p) { return __uint_as_float(p & 0xffff0000u); }

// ---------------------------------------------------------------------------
// Cast + transpose W (128x128 fp32, k-major) -> WT bf16 (n-major).
// Also zeroes gcur (replaces a memset dispatch; runs before proj_p1).
// ---------------------------------------------------------------------------
__global__ __launch_bounds__(128) void cast_wt(
    const float* __restrict__ WQ, const float* __restrict__ WK,
    const float* __restrict__ WV, unsigned short* __restrict__ WT,
    int* __restrict__ gcur)
{
    if (blockIdx.x == 0) {
        gcur[threadIdx.x] = 0;
        gcur[threadIdx.x + 128] = 0;
    }
    const int w = blockIdx.x >> 7;
    const int n = blockIdx.x & 127;
    const int k = threadIdx.x;
    const float* W = (w == 0) ? WQ : ((w == 1) ? WK : WV);
    WT[w * 16384 + n * 128 + k] = f2bf(W[k * 128 + n]);
}

// ---------------------------------------------------------------------------
// MERGED dispatch: blockIdx parity selects role.
//   role 0 (even blocks, 782): fused QKV projection (bf16 MFMA 16x16x32),
//     identical to the verified proj_mfma. MFMA/VALU-heavy.
//   role 1 (odd blocks, 782): counting-sort pass 1 (bucket by dst>>8),
//     memory/LDS-atomic-heavy. Packs (bucket<<24 | src<<16b.. ) -- global
//     word is (src<<8 | dst&255), 4B/edge (src<65536): halves pass1's
//     scattered writes AND pass2's reads vs the old dbuf+sbuf pair.
// The two roles are independent (proj needs WT; pass1 needs gcur=0; both
// produced by cast_wt) and have complementary bottlenecks, so interleaving
// them in one grid overlaps what used to be two serial dispatches.
// LDS is overlaid: proj's 33.8KB lbuf vs pass1's ~11.3KB tables.
// Scans use wave shfl_up + 4-entry combine (5 barriers vs 20).
// ---------------------------------------------------------------------------
__global__ __launch_bounds__(256) void proj_p1(
    const float* __restrict__ state, const unsigned short* __restrict__ WT,
    const float* __restrict__ bQ, const float* __restrict__ bK,
    const float* __restrict__ bV,
    unsigned short* __restrict__ Qb, unsigned short* __restrict__ KVb,
    const int* __restrict__ src, const int* __restrict__ dst,
    int* __restrict__ gcur, int* __restrict__ pbuf)
{
    __shared__ int smem[4 * 16 * 132];     // 33.8 KB, overlaid per role

    const int role = blockIdx.x & 1;
    const int bid  = blockIdx.x >> 1;
    const int t    = threadIdx.x;

    if (role == 0) {
        // ------------------------- projection -------------------------
        float* lbufA = (float*)smem;
        const int wv   = t >> 6;
        const int lane = t & 63;
        const int lm   = lane & 15;
        const int quad = lane >> 4;
        const int m0   = bid * 64 + wv * 16;
        const int m    = m0 + lm;

        fp32x4 acc[3][8];
#pragma unroll
        for (int w = 0; w < 3; ++w)
#pragma unroll
            for (int tt = 0; tt < 8; ++tt)
                acc[w][tt] = (fp32x4){0.f, 0.f, 0.f, 0.f};

        const int kq = quad * 8;
#pragma unroll
        for (int kb = 0; kb < 128; kb += 32) {
            short8 a = (short8){0,0,0,0,0,0,0,0};
            if (m < NNODES) {
                const float4 f0 = *(const float4*)(state + (size_t)m * 128 + kb + kq);
                const float4 f1 = *(const float4*)(state + (size_t)m * 128 + kb + kq + 4);
                a[0] = (short)f2bf(f0.x); a[1] = (short)f2bf(f0.y);
                a[2] = (short)f2bf(f0.z); a[3] = (short)f2bf(f0.w);
                a[4] = (short)f2bf(f1.x); a[5] = (short)f2bf(f1.y);
                a[6] = (short)f2bf(f1.z); a[7] = (short)f2bf(f1.w);
            }
#pragma unroll
            for (int w = 0; w < 3; ++w) {
#pragma unroll
                for (int tt = 0; tt < 8; ++tt) {
                    const short8 b = *(const short8*)(WT + w * 16384 + (tt * 16 + lm) * 128 + kb + kq);
                    acc[w][tt] = __builtin_amdgcn_mfma_f32_16x16x32_bf16(a, b, acc[w][tt], 0, 0, 0);
                }
            }
        }

        const int rrow = lane >> 2;          // 0..15
        const int rcol = (lane & 3) * 32;    // 0,32,64,96
        const int grow = m0 + rrow;
#pragma unroll
        for (int w = 0; w < 3; ++w) {
            const float* bp = (w == 0) ? bQ : ((w == 1) ? bK : bV);
            float* L = lbufA + wv * (16 * 132);
#pragma unroll
            for (int tt = 0; tt < 8; ++tt) {
                const float bb = bp[tt * 16 + lm];
#pragma unroll
                for (int r = 0; r < 4; ++r)
                    L[(quad * 4 + r) * 132 + tt * 16 + lm] = acc[w][tt][r] + bb;
            }
            __syncthreads();
            if (grow < NNODES) {
                unsigned short* gp;
                if (w == 0)      gp = Qb  + (size_t)grow * 128 + rcol;
                else if (w == 1) gp = KVb + (size_t)grow * 256 + rcol;
                else             gp = KVb + (size_t)grow * 256 + 128 + rcol;
#pragma unroll
                for (int c = 0; c < 4; ++c) {
                    const float* lp = &L[rrow * 132 + rcol + c * 8];   // 16B aligned
                    const float4 x0 = *(const float4*)(lp);
                    const float4 x1 = *(const float4*)(lp + 4);
                    short8 r;
                    r[0] = (short)f2bf(x0.x); r[1] = (short)f2bf(x0.y);
                    r[2] = (short)f2bf(x0.z); r[3] = (short)f2bf(x0.w);
                    r[4] = (short)f2bf(x1.x); r[5] = (short)f2bf(x1.y);
                    r[6] = (short)f2bf(x1.z); r[7] = (short)f2bf(x1.w);
                    *(short8*)(gp + c * 8) = r;
                }
            }
            __syncthreads();
        }
    } else {
        // ------------------------- bucket pass 1 -------------------------
        int* hist  = smem;            // 256
        int* lofs  = smem + 256;      // 256
        int* gbase = smem + 512;      // 256
        int* wsum  = smem + 768;      // 4
        int* pktg  = smem + 1024;     // 2048 staged packed words

        hist[t] = 0;
        __syncthreads();

        const long long e0 = (long long)bid * 2048 + t * 8;
        const bool valid = (e0 < NEDGES);
        unsigned int w8[8]; int b8[8], r8[8];
        if (valid) {
            const int4 sA = *(const int4*)(src + e0);
            const int4 sB = *(const int4*)(src + e0 + 4);
            const int4 dA = *(const int4*)(dst + e0);
            const int4 dB = *(const int4*)(dst + e0 + 4);
            const int dd[8] = {dA.x, dA.y, dA.z, dA.w, dB.x, dB.y, dB.z, dB.w};
            const int ss[8] = {sA.x, sA.y, sA.z, sA.w, sB.x, sB.y, sB.z, sB.w};
#pragma unroll
            for (int j = 0; j < 8; ++j) {
                const int bb = dd[j] >> 8;
                b8[j] = bb;
                w8[j] = ((unsigned)bb << 24) | ((unsigned)ss[j] << 8) | (unsigned)(dd[j] & 255);
                r8[j] = atomicAdd(&hist[bb], 1);
            }
        }
        __syncthreads();

        const int v = hist[t];
        if (t < NB && v > 0) gbase[t] = atomicAdd(&gcur[t], v);

        // wave-level inclusive scan + 4-wave combine (replaces 16-barrier scan)
        int x = v;
#pragma unroll
        for (int off = 1; off < 64; off <<= 1) {
            const int y = __shfl_up(x, off);
            if ((t & 63) >= off) x += y;
        }
        if ((t & 63) == 63) wsum[t >> 6] = x;
        __syncthreads();
        int pre = 0;
#pragma unroll
        for (int ww = 0; ww < 4; ++ww)
            if (ww < (t >> 6)) pre += wsum[ww];
        const int tot = wsum[0] + wsum[1] + wsum[2] + wsum[3];
        lofs[t] = x + pre - v;          // exclusive prefix
        __syncthreads();

        if (valid) {
#pragma unroll
            for (int j = 0; j < 8; ++j)
                pktg[lofs[b8[j]] + r8[j]] = (int)w8[j];
        }
        __syncthreads();

#pragma unroll
        for (int j = 0; j < 8; ++j) {
            const int slot = t + 256 * j;
            if (slot < tot) {
                const unsigned int w = (unsigned int)pktg[slot];
                const int bb = (int)(w >> 24);
                const long long g = (long long)bb * BCAP + gbase[bb] + (slot - lofs[bb]);
                pbuf[g] = (int)(w & 0x00FFFFFFu);
            }
        }
    }
}

// ---------------------------------------------------------------------------
// Counting-sort pass 2: one block per bucket, 1024 threads. Reads the packed
// word once (4B/edge, coalesced), stages it in LDS, LDS-groups by dst&255,
// writes eidx coalesced. Wave shfl_up scan (5 barriers total).
// ---------------------------------------------------------------------------
__global__ __launch_bounds__(1024) void bucket_pass2(
    const int* __restrict__ pbuf, const int* __restrict__ gcur,
    int* __restrict__ eidx, int2* __restrict__ offs2)
{
    __shared__ int hist[256];
    __shared__ int cur[256];
    __shared__ int wsum[4];
    __shared__ int pstash[BCAP];    // 40 KB packed words
    __shared__ int srcbuf[BCAP];    // 40 KB grouped src ids

    const int b = blockIdx.x;
    const int t = threadIdx.x;
    int cnt = gcur[b];
    if (cnt > BCAP) cnt = BCAP;
    const long long base = (long long)b * BCAP;

    if (t < 256) hist[t] = 0;
    __syncthreads();

    for (int i = t; i < cnt; i += 1024) {
        const int g = pbuf[base + i];
        pstash[i] = g;
        atomicAdd(&hist[g & 255], 1);
    }
    __syncthreads();

    int x = 0, v = 0;
    if (t < 256) {
        v = hist[t];
        x = v;
#pragma unroll
        for (int off = 1; off < 64; off <<= 1) {
            const int y = __shfl_up(x, off);
            if ((t & 63) >= off) x += y;
        }
        if ((t & 63) == 63) wsum[t >> 6] = x;
    }
    __syncthreads();
    if (t < 256) {
        int pre = 0;
#pragma unroll
        for (int ww = 0; ww < 4; ++ww)
            if (ww < (t >> 6)) pre += wsum[ww];
        const int ex = x + pre - v;          // exclusive
        cur[t] = ex;
        const int n = b * 256 + t;
        if (n < NNODES) {
            int2 oe; oe.x = (int)(base + ex); oe.y = (int)(base + ex + v);
            offs2[n] = oe;
        }
    }
    __syncthreads();

    for (int i = t; i < cnt; i += 1024) {
        const int g = pstash[i];
        const int p = atomicAdd(&cur[g & 255], 1);
        srcbuf[p] = g >> 8;
    }
    __syncthreads();

    for (int i = t; i < cnt; i += 1024)
        eidx[base + i] = srcbuf[i];
}

// ---------------------------------------------------------------------------
// Aggregation: one wave per dst node; lane = (edge-slot eo=l>>3, head h=l&7).
// Reverted verbatim to the best-measured version (round 0: 102.5us, absmax
// 0.0234). Rounds 1-3 showed this kernel is pinned at ~103us by random-gather
// memory behavior: insensitive to index prefetch, to 3x concurrency, and the
// fp8-K byte cut failed accuracy (exp turns score abs-error into weight
// rel-error). Treated as locally converged.
// ---------------------------------------------------------------------------
__global__ __launch_bounds__(256) void aggregate_kernel(
    const int* __restrict__ eidx, const int2* __restrict__ offs2,
    const unsigned short* __restrict__ Qb, const unsigned short* __restrict__ KVb,
    float* __restrict__ out)
{
    const int n = blockIdx.x * 4 + (threadIdx.x >> 6);
    const int l = threadIdx.x & 63;
    if (n >= NNODES) return;
    const int eo = l >> 3;       // edge slot 0..7
    const int h  = l & 7;        // head 0..7

    const unsigned short* qp = Qb + (size_t)n * 128 + h * 16;
    const uint4 qa = *(const uint4*)(qp);
    const uint4 qc = *(const uint4*)(qp + 8);
    float q[16];
    q[0]  = bflo(qa.x); q[1]  = bfhi(qa.x); q[2]  = bflo(qa.y); q[3]  = bfhi(qa.y);
    q[4]  = bflo(qa.z); q[5]  = bfhi(qa.z); q[6]  = bflo(qa.w); q[7]  = bfhi(qa.w);
    q[8]  = bflo(qc.x); q[9]  = bfhi(qc.x); q[10] = bflo(qc.y); q[11] = bfhi(qc.y);
    q[12] = bflo(qc.z); q[13] = bfhi(qc.z); q[14] = bflo(qc.w); q[15] = bfhi(qc.w);

    const int2 oe = offs2[n];
    const int beg = oe.x, end = oe.y;

    float acc[16];
#pragma unroll
    for (int j = 0; j < 16; ++j) acc[j] = 0.f;
    float zacc = 0.f;

    for (int i = beg; i < end; i += 16) {
        const int ei0 = i + eo;
        const int ei1 = ei0 + 8;
        const bool act0 = (ei0 < end);
        const bool act1 = (ei1 < end);
        const int s0 = eidx[act0 ? ei0 : beg];
        const int s1 = eidx[act1 ? ei1 : beg];

        const unsigned short* kp0 = KVb + (size_t)s0 * 256 + h * 16;
        const unsigned short* kp1 = KVb + (size_t)s1 * 256 + h * 16;
        const uint4 ka0 = *(const uint4*)(kp0);
        const uint4 kc0 = *(const uint4*)(kp0 + 8);
        const uint4 va0 = *(const uint4*)(kp0 + 128);
        const uint4 vc0 = *(const uint4*)(kp0 + 136);
        const uint4 ka1 = *(const uint4*)(kp1);
        const uint4 kc1 = *(const uint4*)(kp1 + 8);
        const uint4 va1 = *(const uint4*)(kp1 + 128);
        const uint4 vc1 = *(const uint4*)(kp1 + 136);

        float p0;
        p0 = fmaf(bfhi(ka0.x), q[1],  bflo(ka0.x) * q[0]);
        p0 = fmaf(bflo(ka0.y), q[2],  p0); p0 = fmaf(bfhi(ka0.y), q[3],  p0);
        p0 = fmaf(bflo(ka0.z), q[4],  p0); p0 = fmaf(bfhi(ka0.z), q[5],  p0);
        p0 = fmaf(bflo(ka0.w), q[6],  p0); p0 = fmaf(bfhi(ka0.w), q[7],  p0);
        p0 = fmaf(bflo(kc0.x), q[8],  p0); p0 = fmaf(bfhi(kc0.x), q[9],  p0);
        p0 = fmaf(bflo(kc0.y), q[10], p0); p0 = fmaf(bfhi(kc0.y), q[11], p0);
        p0 = fmaf(bflo(kc0.z), q[12], p0); p0 = fmaf(bfhi(kc0.z), q[13], p0);
        p0 = fmaf(bflo(kc0.w), q[14], p0); p0 = fmaf(bfhi(kc0.w), q[15], p0);

        float p1;
        p1 = fmaf(bfhi(ka1.x), q[1],  bflo(ka1.x) * q[0]);
        p1 = fmaf(bflo(ka1.y), q[2],  p1); p1 = fmaf(bfhi(ka1.y), q[3],  p1);
        p1 = fmaf(bflo(ka1.z), q[4],  p1); p1 = fmaf(bfhi(ka1.z), q[5],  p1);
        p1 = fmaf(bflo(ka1.w), q[6],  p1); p1 = fmaf(bfhi(ka1.w), q[7],  p1);
        p1 = fmaf(bflo(kc1.x), q[8],  p1); p1 = fmaf(bfhi(kc1.x), q[9],  p1);
        p1 = fmaf(bflo(kc1.y), q[10], p1); p1 = fmaf(bfhi(kc1.y), q[11], p1);
        p1 = fmaf(bflo(kc1.z), q[12], p1); p1 = fmaf(bfhi(kc1.z), q[13], p1);
        p1 = fmaf(bflo(kc1.w), q[14], p1); p1 = fmaf(bfhi(kc1.w), q[15], p1);

        float w0 = __expf(fminf(fmaxf(p0 * 0.25f, -5.f), 5.f));
        float w1 = __expf(fminf(fmaxf(p1 * 0.25f, -5.f), 5.f));
        w0 = act0 ? w0 : 0.f;
        w1 = act1 ? w1 : 0.f;
        zacc += w0 + w1;

        acc[0]  = fmaf(bflo(va0.x), w0, acc[0]);  acc[1]  = fmaf(bfhi(va0.x), w0, acc[1]);
        acc[2]  = fmaf(bflo(va0.y), w0, acc[2]);  acc[3]  = fmaf(bfhi(va0.y), w0, acc[3]);
        acc[4]  = fmaf(bflo(va0.z), w0, acc[4]);  acc[5]  = fmaf(bfhi(va0.z), w0, acc[5]);
        acc[6]  = fmaf(bflo(va0.w), w0, acc[6]);  acc[7]  = fmaf(bfhi(va0.w), w0, acc[7]);
        acc[8]  = fmaf(bflo(vc0.x), w0, acc[8]);  acc[9]  = fmaf(bfhi(vc0.x), w0, acc[9]);
        acc[10] = fmaf(bflo(vc0.y), w0, acc[10]); acc[11] = fmaf(bfhi(vc0.y), w0, acc[11]);
        acc[12] = fmaf(bflo(vc0.z), w0, acc[12]); acc[13] = fmaf(bfhi(vc0.z), w0, acc[13]);
        acc[14] = fmaf(bflo(vc0.w), w0, acc[14]); acc[15] = fmaf(bfhi(vc0.w), w0, acc[15]);

        acc[0]  = fmaf(bflo(va1.x), w1, acc[0]);  acc[1]  = fmaf(bfhi(va1.x), w1, acc[1]);
        acc[2]  = fmaf(bflo(va1.y), w1, acc[2]);  acc[3]  = fmaf(bfhi(va1.y), w1, acc[3]);
        acc[4]  = fmaf(bflo(va1.z), w1, acc[4]);  acc[5]  = fmaf(bfhi(va1.z), w1, acc[5]);
        acc[6]  = fmaf(bflo(va1.w), w1, acc[6]);  acc[7]  = fmaf(bfhi(va1.w), w1, acc[7]);
        acc[8]  = fmaf(bflo(vc1.x), w1, acc[8]);  acc[9]  = fmaf(bfhi(vc1.x), w1, acc[9]);
        acc[10] = fmaf(bflo(vc1.y), w1, acc[10]); acc[11] = fmaf(bfhi(vc1.y), w1, acc[11]);
        acc[12] = fmaf(bflo(vc1.z), w1, acc[12]); acc[13] = fmaf(bfhi(vc1.z), w1, acc[13]);
        acc[14] = fmaf(bflo(vc1.w), w1, acc[14]); acc[15] = fmaf(bfhi(vc1.w), w1, acc[15]);
    }

    // reduce across edge slots (lanes differing in bits 3..5)
#pragma unroll
    for (int st = 8; st < 64; st <<= 1) {
        zacc += __shfl_xor(zacc, st);
#pragma unroll
        for (int j = 0; j < 16; ++j) acc[j] += __shfl_xor(acc[j], st);
    }

    if (eo == 0) {
        const float inv = 1.0f / zacc;
        float* op = out + (size_t)n * 128 + h * 16;
        *(float4*)(op)      = make_float4(acc[0]*inv,  acc[1]*inv,  acc[2]*inv,  acc[3]*inv);
        *(float4*)(op + 4)  = make_float4(acc[4]*inv,  acc[5]*inv,  acc[6]*inv,  acc[7]*inv);
        *(float4*)(op + 8)  = make_float4(acc[8]*inv,  acc[9]*inv,  acc[10]*inv, acc[11]*inv);
        *(float4*)(op + 12) = make_float4(acc[12]*inv, acc[13]*inv, acc[14]*inv, acc[15]*inv);
    }
}

extern "C" void kernel_launch(void* const* d_in, const int* in_sizes, int n_in,
                              void* d_out, int out_size, void* d_ws, size_t ws_size,
                              hipStream_t stream)
{
    const float* state = (const float*)d_in[0];
    const int*   src   = (const int*)d_in[1];
    const int*   dst   = (const int*)d_in[2];
    const float* WQ    = (const float*)d_in[3];
    const float* bQ    = (const float*)d_in[4];
    const float* WK    = (const float*)d_in[5];
    const float* bK    = (const float*)d_in[6];
    const float* WV    = (const float*)d_in[7];
    const float* bV    = (const float*)d_in[8];
    float* out = (float*)d_out;

    unsigned short* Qb  = (unsigned short*)d_ws;                 // 12.8 MB
    unsigned short* KVb = Qb + (size_t)NNODES * 128;             // 25.6 MB
    unsigned short* WT  = KVb + (size_t)NNODES * 256;            // 96 KB
    int* pbuf  = (int*)(WT + 3 * 16384);                         // NB*BCAP*4B packed
    int* eidx  = pbuf + (size_t)NB * BCAP;
    int* gcur  = eidx + (size_t)NB * BCAP;                       // 256
    int2* offs2 = (int2*)(gcur + 256);                           // 50000 int2

    cast_wt<<<3 * 128, 128, 0, stream>>>(WQ, WK, WV, WT, gcur);
    proj_p1<<<2 * P1B, 256, 0, stream>>>(state, WT, bQ, bK, bV, Qb, KVb,
                                         src, dst, gcur, pbuf);
    bucket_pass2<<<NB, 1024, 0, stream>>>(pbuf, gcur, eidx, offs2);
    aggregate_kernel<<<(NNODES + 3) / 4, 256, 0, stream>>>(eidx, offs2, Qb, KVb, out);
}

// Round 5
// 279.209 us; speedup vs baseline: 1.0913x; 1.0913x over previous
//
#include <hip/hip_runtime.h>

#define NNODES 50000
#define NEDGES 1600000
#define NB 196        // buckets = dst>>8  (50000/256 -> 0..195)
#define BCAP 10240    // edges per bucket capacity (mean 8163, +20 sigma)

typedef __attribute__((ext_vector_type(8))) short short8;   // 8 x bf16
typedef __attribute__((ext_vector_type(4))) float fp32x4;   // MFMA C/D frag

__device__ __forceinline__ unsigned short f2bf(float f) {   // RNE fp32 -> bf16
    unsigned int u = __float_as_uint(f);
    u += 0x7fffu + ((u >> 16) & 1u);
    return (unsigned short)(u >> 16);
}
__device__ __forceinline__ float bflo(unsigned int p) { return __uint_as_float(p << 16); }
__device__ __forceinline__ float bfhi(unsigned int p) { return __uint_as_float(p & 0xffff0000u); }

// ---------------------------------------------------------------------------
// Cast + transpose W (128x128 fp32, k-major) -> WT bf16 (n-major).
// Also zeroes gcur (replaces a memset dispatch; runs before pass1 in-stream).
// ---------------------------------------------------------------------------
__global__ __launch_bounds__(128) void cast_wt(
    const float* __restrict__ WQ, const float* __restrict__ WK,
    const float* __restrict__ WV, unsigned short* __restrict__ WT,
    int* __restrict__ gcur)
{
    if (blockIdx.x == 0) {
        gcur[threadIdx.x] = 0;
        gcur[threadIdx.x + 128] = 0;
    }
    const int w = blockIdx.x >> 7;
    const int n = blockIdx.x & 127;
    const int k = threadIdx.x;
    const float* W = (w == 0) ? WQ : ((w == 1) ? WK : WV);
    WT[w * 16384 + n * 128 + k] = f2bf(W[k * 128 + n]);
}

// ---------------------------------------------------------------------------
// Fused QKV projection, bf16 MFMA 16x16x32, fp32 state read + in-register
// cast. Outputs: Qb [n][128] bf16, KVb [n][256] bf16 (K cols 0..127, V cols
// 128..255). Epilogue: bias add + LDS transpose -> coalesced bf16x8 stores.
// Byte-identical to the round-1 verified version (round-4 lesson: do not
// entangle this kernel's 108-VGPR/33.8KB-LDS footprint with the sort passes).
// ---------------------------------------------------------------------------
__global__ __launch_bounds__(256) void proj_mfma(
    const float* __restrict__ state, const unsigned short* __restrict__ WT,
    const float* __restrict__ bQ, const float* __restrict__ bK,
    const float* __restrict__ bV,
    unsigned short* __restrict__ Qb, unsigned short* __restrict__ KVb)
{
    __shared__ float lbuf[4][16 * 132];

    const int tid  = threadIdx.x;
    const int wv   = tid >> 6;
    const int lane = tid & 63;
    const int lm   = lane & 15;    // A row / B col / C col within tile
    const int quad = lane >> 4;    // k-chunk select, C row group
    const int m0   = blockIdx.x * 64 + wv * 16;
    const int m    = m0 + lm;

    fp32x4 acc[3][8];
#pragma unroll
    for (int w = 0; w < 3; ++w)
#pragma unroll
        for (int t = 0; t < 8; ++t)
            acc[w][t] = (fp32x4){0.f, 0.f, 0.f, 0.f};

    const int kq = quad * 8;
#pragma unroll
    for (int kb = 0; kb < 128; kb += 32) {
        short8 a = (short8){0,0,0,0,0,0,0,0};
        if (m < NNODES) {
            const float4 f0 = *(const float4*)(state + (size_t)m * 128 + kb + kq);
            const float4 f1 = *(const float4*)(state + (size_t)m * 128 + kb + kq + 4);
            a[0] = (short)f2bf(f0.x); a[1] = (short)f2bf(f0.y);
            a[2] = (short)f2bf(f0.z); a[3] = (short)f2bf(f0.w);
            a[4] = (short)f2bf(f1.x); a[5] = (short)f2bf(f1.y);
            a[6] = (short)f2bf(f1.z); a[7] = (short)f2bf(f1.w);
        }
#pragma unroll
        for (int w = 0; w < 3; ++w) {
#pragma unroll
            for (int t = 0; t < 8; ++t) {
                const short8 b = *(const short8*)(WT + w * 16384 + (t * 16 + lm) * 128 + kb + kq);
                acc[w][t] = __builtin_amdgcn_mfma_f32_16x16x32_bf16(a, b, acc[w][t], 0, 0, 0);
            }
        }
    }

    const int rrow = lane >> 2;          // 0..15
    const int rcol = (lane & 3) * 32;    // 0,32,64,96
    const int grow = m0 + rrow;
#pragma unroll
    for (int w = 0; w < 3; ++w) {
        const float* bp = (w == 0) ? bQ : ((w == 1) ? bK : bV);
        float* L = &lbuf[wv][0];
#pragma unroll
        for (int t = 0; t < 8; ++t) {
            const float bb = bp[t * 16 + lm];
#pragma unroll
            for (int r = 0; r < 4; ++r)
                L[(quad * 4 + r) * 132 + t * 16 + lm] = acc[w][t][r] + bb;
        }
        __syncthreads();
        if (grow < NNODES) {
            unsigned short* gp;
            if (w == 0)      gp = Qb  + (size_t)grow * 128 + rcol;
            else if (w == 1) gp = KVb + (size_t)grow * 256 + rcol;
            else             gp = KVb + (size_t)grow * 256 + 128 + rcol;
#pragma unroll
            for (int c = 0; c < 4; ++c) {
                const float* lp = &L[rrow * 132 + rcol + c * 8];   // 16B aligned
                const float4 x0 = *(const float4*)(lp);
                const float4 x1 = *(const float4*)(lp + 4);
                short8 r;
                r[0] = (short)f2bf(x0.x); r[1] = (short)f2bf(x0.y);
                r[2] = (short)f2bf(x0.z); r[3] = (short)f2bf(x0.w);
                r[4] = (short)f2bf(x1.x); r[5] = (short)f2bf(x1.y);
                r[6] = (short)f2bf(x1.z); r[7] = (short)f2bf(x1.w);
                *(short8*)(gp + c * 8) = r;
            }
        }
        __syncthreads();
    }
}

// ---------------------------------------------------------------------------
// Counting-sort pass 1 (standalone, small footprint -> high occupancy).
// 2048 edges/block. Packs (bucket<<24 | src<<8 | dstlow) into ONE word:
// halves the scattered global write traffic and the LDS staging vs the old
// dbuf+sbuf pair. Wave shfl_up scan + 4-wave combine (5 barriers vs 20).
// ---------------------------------------------------------------------------
__global__ __launch_bounds__(256) void bucket_pass1(
    const int* __restrict__ src, const int* __restrict__ dst,
    int* __restrict__ gcur, int* __restrict__ pbuf)
{
    __shared__ int hist[256];
    __shared__ int lofs[256];
    __shared__ int gbase[256];
    __shared__ int wsum[4];
    __shared__ int pktg[2048];

    const int t = threadIdx.x;
    hist[t] = 0;
    __syncthreads();

    const long long e0 = (long long)blockIdx.x * 2048 + t * 8;
    const bool valid = (e0 < NEDGES);
    unsigned int w8[8]; int b8[8], r8[8];
    if (valid) {
        const int4 sA = *(const int4*)(src + e0);
        const int4 sB = *(const int4*)(src + e0 + 4);
        const int4 dA = *(const int4*)(dst + e0);
        const int4 dB = *(const int4*)(dst + e0 + 4);
        const int dd[8] = {dA.x, dA.y, dA.z, dA.w, dB.x, dB.y, dB.z, dB.w};
        const int ss[8] = {sA.x, sA.y, sA.z, sA.w, sB.x, sB.y, sB.z, sB.w};
#pragma unroll
        for (int j = 0; j < 8; ++j) {
            const int bb = dd[j] >> 8;
            b8[j] = bb;
            w8[j] = ((unsigned)bb << 24) | ((unsigned)ss[j] << 8) | (unsigned)(dd[j] & 255);
            r8[j] = atomicAdd(&hist[bb], 1);
        }
    }
    __syncthreads();

    const int v = hist[t];
    if (t < NB && v > 0) gbase[t] = atomicAdd(&gcur[t], v);

    // wave-level inclusive scan + 4-wave combine
    int x = v;
#pragma unroll
    for (int off = 1; off < 64; off <<= 1) {
        const int y = __shfl_up(x, off);
        if ((t & 63) >= off) x += y;
    }
    if ((t & 63) == 63) wsum[t >> 6] = x;
    __syncthreads();
    int pre = 0;
#pragma unroll
    for (int ww = 0; ww < 4; ++ww)
        if (ww < (t >> 6)) pre += wsum[ww];
    const int tot = wsum[0] + wsum[1] + wsum[2] + wsum[3];
    lofs[t] = x + pre - v;          // exclusive prefix
    __syncthreads();

    if (valid) {
#pragma unroll
        for (int j = 0; j < 8; ++j)
            pktg[lofs[b8[j]] + r8[j]] = (int)w8[j];
    }
    __syncthreads();

#pragma unroll
    for (int j = 0; j < 8; ++j) {
        const int slot = t + 256 * j;
        if (slot < tot) {
            const unsigned int w = (unsigned int)pktg[slot];
            const int bb = (int)(w >> 24);
            const long long g = (long long)bb * BCAP + gbase[bb] + (slot - lofs[bb]);
            pbuf[g] = (int)(w & 0x00FFFFFFu);
        }
    }
}

// ---------------------------------------------------------------------------
// Counting-sort pass 2: one block per bucket, 1024 threads (latency-bound at
// grid=196; wide block proven -16us in round 1). Reads the packed word once
// (4B/edge, coalesced, half the old dbuf+sbuf traffic), stages in LDS,
// LDS-groups by dst&255, writes eidx coalesced. Wave shfl_up scan.
// ---------------------------------------------------------------------------
__global__ __launch_bounds__(1024) void bucket_pass2(
    const int* __restrict__ pbuf, const int* __restrict__ gcur,
    int* __restrict__ eidx, int2* __restrict__ offs2)
{
    __shared__ int hist[256];
    __shared__ int cur[256];
    __shared__ int wsum[4];
    __shared__ int pstash[BCAP];    // 40 KB packed words
    __shared__ int srcbuf[BCAP];    // 40 KB grouped src ids

    const int b = blockIdx.x;
    const int t = threadIdx.x;
    int cnt = gcur[b];
    if (cnt > BCAP) cnt = BCAP;
    const long long base = (long long)b * BCAP;

    if (t < 256) hist[t] = 0;
    __syncthreads();

    for (int i = t; i < cnt; i += 1024) {
        const int g = pbuf[base + i];
        pstash[i] = g;
        atomicAdd(&hist[g & 255], 1);
    }
    __syncthreads();

    int x = 0, v = 0;
    if (t < 256) {
        v = hist[t];
        x = v;
#pragma unroll
        for (int off = 1; off < 64; off <<= 1) {
            const int y = __shfl_up(x, off);
            if ((t & 63) >= off) x += y;
        }
        if ((t & 63) == 63) wsum[t >> 6] = x;
    }
    __syncthreads();
    if (t < 256) {
        int pre = 0;
#pragma unroll
        for (int ww = 0; ww < 4; ++ww)
            if (ww < (t >> 6)) pre += wsum[ww];
        const int ex = x + pre - v;          // exclusive
        cur[t] = ex;
        const int n = b * 256 + t;
        if (n < NNODES) {
            int2 oe; oe.x = (int)(base + ex); oe.y = (int)(base + ex + v);
            offs2[n] = oe;
        }
    }
    __syncthreads();

    for (int i = t; i < cnt; i += 1024) {
        const int g = pstash[i];
        const int p = atomicAdd(&cur[g & 255], 1);
        srcbuf[p] = g >> 8;
    }
    __syncthreads();

    for (int i = t; i < cnt; i += 1024)
        eidx[base + i] = srcbuf[i];
}

// ---------------------------------------------------------------------------
// Aggregation: one wave per dst node; lane = (edge-slot eo=l>>3, head h=l&7).
// Round-0 verbatim body (best measured 102.5us, absmax 0.0234). Established
// locally converged: insensitive to index prefetch (r1), to 3x concurrency
// (r2); fp8-K byte cut failed accuracy (r3). ~103us = random-gather memory
// ceiling at ~8 TB/s effective L2-side demand.
// ---------------------------------------------------------------------------
__global__ __launch_bounds__(256) void aggregate_kernel(
    const int* __restrict__ eidx, const int2* __restrict__ offs2,
    const unsigned short* __restrict__ Qb, const unsigned short* __restrict__ KVb,
    float* __restrict__ out)
{
    const int n = blockIdx.x * 4 + (threadIdx.x >> 6);
    const int l = threadIdx.x & 63;
    if (n >= NNODES) return;
    const int eo = l >> 3;       // edge slot 0..7
    const int h  = l & 7;        // head 0..7

    const unsigned short* qp = Qb + (size_t)n * 128 + h * 16;
    const uint4 qa = *(const uint4*)(qp);
    const uint4 qc = *(const uint4*)(qp + 8);
    float q[16];
    q[0]  = bflo(qa.x); q[1]  = bfhi(qa.x); q[2]  = bflo(qa.y); q[3]  = bfhi(qa.y);
    q[4]  = bflo(qa.z); q[5]  = bfhi(qa.z); q[6]  = bflo(qa.w); q[7]  = bfhi(qa.w);
    q[8]  = bflo(qc.x); q[9]  = bfhi(qc.x); q[10] = bflo(qc.y); q[11] = bfhi(qc.y);
    q[12] = bflo(qc.z); q[13] = bfhi(qc.z); q[14] = bflo(qc.w); q[15] = bfhi(qc.w);

    const int2 oe = offs2[n];
    const int beg = oe.x, end = oe.y;

    float acc[16];
#pragma unroll
    for (int j = 0; j < 16; ++j) acc[j] = 0.f;
    float zacc = 0.f;

    for (int i = beg; i < end; i += 16) {
        const int ei0 = i + eo;
        const int ei1 = ei0 + 8;
        const bool act0 = (ei0 < end);
        const bool act1 = (ei1 < end);
        const int s0 = eidx[act0 ? ei0 : beg];
        const int s1 = eidx[act1 ? ei1 : beg];

        const unsigned short* kp0 = KVb + (size_t)s0 * 256 + h * 16;
        const unsigned short* kp1 = KVb + (size_t)s1 * 256 + h * 16;
        const uint4 ka0 = *(const uint4*)(kp0);
        const uint4 kc0 = *(const uint4*)(kp0 + 8);
        const uint4 va0 = *(const uint4*)(kp0 + 128);
        const uint4 vc0 = *(const uint4*)(kp0 + 136);
        const uint4 ka1 = *(const uint4*)(kp1);
        const uint4 kc1 = *(const uint4*)(kp1 + 8);
        const uint4 va1 = *(const uint4*)(kp1 + 128);
        const uint4 vc1 = *(const uint4*)(kp1 + 136);

        float p0;
        p0 = fmaf(bfhi(ka0.x), q[1],  bflo(ka0.x) * q[0]);
        p0 = fmaf(bflo(ka0.y), q[2],  p0); p0 = fmaf(bfhi(ka0.y), q[3],  p0);
        p0 = fmaf(bflo(ka0.z), q[4],  p0); p0 = fmaf(bfhi(ka0.z), q[5],  p0);
        p0 = fmaf(bflo(ka0.w), q[6],  p0); p0 = fmaf(bfhi(ka0.w), q[7],  p0);
        p0 = fmaf(bflo(kc0.x), q[8],  p0); p0 = fmaf(bfhi(kc0.x), q[9],  p0);
        p0 = fmaf(bflo(kc0.y), q[10], p0); p0 = fmaf(bfhi(kc0.y), q[11], p0);
        p0 = fmaf(bflo(kc0.z), q[12], p0); p0 = fmaf(bfhi(kc0.z), q[13], p0);
        p0 = fmaf(bflo(kc0.w), q[14], p0); p0 = fmaf(bfhi(kc0.w), q[15], p0);

        float p1;
        p1 = fmaf(bfhi(ka1.x), q[1],  bflo(ka1.x) * q[0]);
        p1 = fmaf(bflo(ka1.y), q[2],  p1); p1 = fmaf(bfhi(ka1.y), q[3],  p1);
        p1 = fmaf(bflo(ka1.z), q[4],  p1); p1 = fmaf(bfhi(ka1.z), q[5],  p1);
        p1 = fmaf(bflo(ka1.w), q[6],  p1); p1 = fmaf(bfhi(ka1.w), q[7],  p1);
        p1 = fmaf(bflo(kc1.x), q[8],  p1); p1 = fmaf(bfhi(kc1.x), q[9],  p1);
        p1 = fmaf(bflo(kc1.y), q[10], p1); p1 = fmaf(bfhi(kc1.y), q[11], p1);
        p1 = fmaf(bflo(kc1.z), q[12], p1); p1 = fmaf(bfhi(kc1.z), q[13], p1);
        p1 = fmaf(bflo(kc1.w), q[14], p1); p1 = fmaf(bfhi(kc1.w), q[15], p1);

        float w0 = __expf(fminf(fmaxf(p0 * 0.25f, -5.f), 5.f));
        float w1 = __expf(fminf(fmaxf(p1 * 0.25f, -5.f), 5.f));
        w0 = act0 ? w0 : 0.f;
        w1 = act1 ? w1 : 0.f;
        zacc += w0 + w1;

        acc[0]  = fmaf(bflo(va0.x), w0, acc[0]);  acc[1]  = fmaf(bfhi(va0.x), w0, acc[1]);
        acc[2]  = fmaf(bflo(va0.y), w0, acc[2]);  acc[3]  = fmaf(bfhi(va0.y), w0, acc[3]);
        acc[4]  = fmaf(bflo(va0.z), w0, acc[4]);  acc[5]  = fmaf(bfhi(va0.z), w0, acc[5]);
        acc[6]  = fmaf(bflo(va0.w), w0, acc[6]);  acc[7]  = fmaf(bfhi(va0.w), w0, acc[7]);
        acc[8]  = fmaf(bflo(vc0.x), w0, acc[8]);  acc[9]  = fmaf(bfhi(vc0.x), w0, acc[9]);
        acc[10] = fmaf(bflo(vc0.y), w0, acc[10]); acc[11] = fmaf(bfhi(vc0.y), w0, acc[11]);
        acc[12] = fmaf(bflo(vc0.z), w0, acc[12]); acc[13] = fmaf(bfhi(vc0.z), w0, acc[13]);
        acc[14] = fmaf(bflo(vc0.w), w0, acc[14]); acc[15] = fmaf(bfhi(vc0.w), w0, acc[15]);

        acc[0]  = fmaf(bflo(va1.x), w1, acc[0]);  acc[1]  = fmaf(bfhi(va1.x), w1, acc[1]);
        acc[2]  = fmaf(bflo(va1.y), w1, acc[2]);  acc[3]  = fmaf(bfhi(va1.y), w1, acc[3]);
        acc[4]  = fmaf(bflo(va1.z), w1, acc[4]);  acc[5]  = fmaf(bfhi(va1.z), w1, acc[5]);
        acc[6]  = fmaf(bflo(va1.w), w1, acc[6]);  acc[7]  = fmaf(bfhi(va1.w), w1, acc[7]);
        acc[8]  = fmaf(bflo(vc1.x), w1, acc[8]);  acc[9]  = fmaf(bfhi(vc1.x), w1, acc[9]);
        acc[10] = fmaf(bflo(vc1.y), w1, acc[10]); acc[11] = fmaf(bfhi(vc1.y), w1, acc[11]);
        acc[12] = fmaf(bflo(vc1.z), w1, acc[12]); acc[13] = fmaf(bfhi(vc1.z), w1, acc[13]);
        acc[14] = fmaf(bflo(vc1.w), w1, acc[14]); acc[15] = fmaf(bfhi(vc1.w), w1, acc[15]);
    }

    // reduce across edge slots (lanes differing in bits 3..5)
#pragma unroll
    for (int st = 8; st < 64; st <<= 1) {
        zacc += __shfl_xor(zacc, st);
#pragma unroll
        for (int j = 0; j < 16; ++j) acc[j] += __shfl_xor(acc[j], st);
    }

    if (eo == 0) {
        const float inv = 1.0f / zacc;
        float* op = out + (size_t)n * 128 + h * 16;
        *(float4*)(op)      = make_float4(acc[0]*inv,  acc[1]*inv,  acc[2]*inv,  acc[3]*inv);
        *(float4*)(op + 4)  = make_float4(acc[4]*inv,  acc[5]*inv,  acc[6]*inv,  acc[7]*inv);
        *(float4*)(op + 8)  = make_float4(acc[8]*inv,  acc[9]*inv,  acc[10]*inv, acc[11]*inv);
        *(float4*)(op + 12) = make_float4(acc[12]*inv, acc[13]*inv, acc[14]*inv, acc[15]*inv);
    }
}

extern "C" void kernel_launch(void* const* d_in, const int* in_sizes, int n_in,
                              void* d_out, int out_size, void* d_ws, size_t ws_size,
                              hipStream_t stream)
{
    const float* state = (const float*)d_in[0];
    const int*   src   = (const int*)d_in[1];
    const int*   dst   = (const int*)d_in[2];
    const float* WQ    = (const float*)d_in[3];
    const float* bQ    = (const float*)d_in[4];
    const float* WK    = (const float*)d_in[5];
    const float* bK    = (const float*)d_in[6];
    const float* WV    = (const float*)d_in[7];
    const float* bV    = (const float*)d_in[8];
    float* out = (float*)d_out;

    unsigned short* Qb  = (unsigned short*)d_ws;                 // 12.8 MB
    unsigned short* KVb = Qb + (size_t)NNODES * 128;             // 25.6 MB
    unsigned short* WT  = KVb + (size_t)NNODES * 256;            // 96 KB
    int* pbuf  = (int*)(WT + 3 * 16384);                         // NB*BCAP*4B packed
    int* eidx  = pbuf + (size_t)NB * BCAP;
    int* gcur  = eidx + (size_t)NB * BCAP;                       // 256
    int2* offs2 = (int2*)(gcur + 256);                           // 50000 int2

    cast_wt<<<3 * 128, 128, 0, stream>>>(WQ, WK, WV, WT, gcur);
    proj_mfma<<<(NNODES + 63) / 64, 256, 0, stream>>>(state, WT, bQ, bK, bV, Qb, KVb);

    bucket_pass1<<<(NEDGES + 2047) / 2048, 256, 0, stream>>>(src, dst, gcur, pbuf);
    bucket_pass2<<<NB, 1024, 0, stream>>>(pbuf, gcur, eidx, offs2);

    aggregate_kernel<<<(NNODES + 3) / 4, 256, 0, stream>>>(eidx, offs2, Qb, KVb, out);
}

// Round 6
// 249.615 us; speedup vs baseline: 1.2207x; 1.1186x over previous
//
#include <hip/hip_runtime.h>

#define NNODES 50000
#define NEDGES 1600000
#define NB 196        // buckets = dst>>8  (50000/256 -> 0..195)
#define BCAP 10240    // edges per bucket capacity (mean 8163, +20 sigma)

typedef __attribute__((ext_vector_type(8))) short short8;   // 8 x bf16
typedef __attribute__((ext_vector_type(4))) float fp32x4;   // MFMA C/D frag

__device__ __forceinline__ unsigned short f2bf(float f) {   // RNE fp32 -> bf16
    unsigned int u = __float_as_uint(f);
    u += 0x7fffu + ((u >> 16) & 1u);
    return (unsigned short)(u >> 16);
}
__device__ __forceinline__ float bflo(unsigned int p) { return __uint_as_float(p << 16); }
__device__ __forceinline__ float bfhi(unsigned int p) { return __uint_as_float(p & 0xffff0000u); }

// signed-byte j of dword u -> float (v_bfe_i32 + v_cvt_f32_i32)
__device__ __forceinline__ float sb2f(unsigned int u, int j) {
    return (float)((int)(u << (24 - 8 * j)) >> 24);
}

// ---------------------------------------------------------------------------
// Cast + transpose W (128x128 fp32, k-major) -> WT bf16 (n-major).
// Also zeroes gcur (replaces a memset dispatch; runs before pass1 in-stream).
// ---------------------------------------------------------------------------
__global__ __launch_bounds__(128) void cast_wt(
    const float* __restrict__ WQ, const float* __restrict__ WK,
    const float* __restrict__ WV, unsigned short* __restrict__ WT,
    int* __restrict__ gcur)
{
    if (blockIdx.x == 0) {
        gcur[threadIdx.x] = 0;
        gcur[threadIdx.x + 128] = 0;
    }
    const int w = blockIdx.x >> 7;
    const int n = blockIdx.x & 127;
    const int k = threadIdx.x;
    const float* W = (w == 0) ? WQ : ((w == 1) ? WK : WV);
    WT[w * 16384 + n * 128 + k] = f2bf(W[k * 128 + n]);
}

// ---------------------------------------------------------------------------
// Fused QKV projection, bf16 MFMA 16x16x32. Outputs:
//   Qb  [n][128] bf16 (unchanged)
//   KVb [n][256] BYTES: [K int8 128B | V int8 128B]  -- 2 cache lines/row
//   scl [n][8] float2: per-(node,head) {kscale, vscale}. kscale folds the
//     1/sqrt(16) score scale (kmax/(127*4)); vscale = vmax/127.
// int8 quantization: round-to-nearest, symmetric, per-head max. Pure bit-math
// software codec (round-3 lesson: fp8 builtin path produced 448-magnitude
// garbage -> never trust a codec you can't unit-reason about).
// Epilogue threads each own 2 complete heads (rcol spans 32 cols) so the
// per-head max needs no cross-lane reduction.
// ---------------------------------------------------------------------------
__global__ __launch_bounds__(256) void proj_mfma(
    const float* __restrict__ state, const unsigned short* __restrict__ WT,
    const float* __restrict__ bQ, const float* __restrict__ bK,
    const float* __restrict__ bV,
    unsigned short* __restrict__ Qb, unsigned char* __restrict__ KVb,
    float* __restrict__ scl)
{
    __shared__ float lbuf[4][16 * 132];

    const int tid  = threadIdx.x;
    const int wv   = tid >> 6;
    const int lane = tid & 63;
    const int lm   = lane & 15;    // A row / B col / C col within tile
    const int quad = lane >> 4;    // k-chunk select, C row group
    const int m0   = blockIdx.x * 64 + wv * 16;
    const int m    = m0 + lm;

    fp32x4 acc[3][8];
#pragma unroll
    for (int w = 0; w < 3; ++w)
#pragma unroll
        for (int t = 0; t < 8; ++t)
            acc[w][t] = (fp32x4){0.f, 0.f, 0.f, 0.f};

    const int kq = quad * 8;
#pragma unroll
    for (int kb = 0; kb < 128; kb += 32) {
        short8 a = (short8){0,0,0,0,0,0,0,0};
        if (m < NNODES) {
            const float4 f0 = *(const float4*)(state + (size_t)m * 128 + kb + kq);
            const float4 f1 = *(const float4*)(state + (size_t)m * 128 + kb + kq + 4);
            a[0] = (short)f2bf(f0.x); a[1] = (short)f2bf(f0.y);
            a[2] = (short)f2bf(f0.z); a[3] = (short)f2bf(f0.w);
            a[4] = (short)f2bf(f1.x); a[5] = (short)f2bf(f1.y);
            a[6] = (short)f2bf(f1.z); a[7] = (short)f2bf(f1.w);
        }
#pragma unroll
        for (int w = 0; w < 3; ++w) {
#pragma unroll
            for (int t = 0; t < 8; ++t) {
                const short8 b = *(const short8*)(WT + w * 16384 + (t * 16 + lm) * 128 + kb + kq);
                acc[w][t] = __builtin_amdgcn_mfma_f32_16x16x32_bf16(a, b, acc[w][t], 0, 0, 0);
            }
        }
    }

    const int rrow = lane >> 2;          // 0..15
    const int rcol = (lane & 3) * 32;    // 0,32,64,96 -> heads h0=(lane&3)*2, h0+1
    const int h0   = (lane & 3) * 2;
    const int grow = m0 + rrow;
#pragma unroll
    for (int w = 0; w < 3; ++w) {
        const float* bp = (w == 0) ? bQ : ((w == 1) ? bK : bV);
        float* L = &lbuf[wv][0];
#pragma unroll
        for (int t = 0; t < 8; ++t) {
            const float bb = bp[t * 16 + lm];
#pragma unroll
            for (int r = 0; r < 4; ++r)
                L[(quad * 4 + r) * 132 + t * 16 + lm] = acc[w][t][r] + bb;
        }
        __syncthreads();
        if (grow < NNODES) {
            float xv[32];
#pragma unroll
            for (int c = 0; c < 4; ++c) {
                const float* lp = &L[rrow * 132 + rcol + c * 8];   // 16B aligned
                const float4 x0 = *(const float4*)(lp);
                const float4 x1 = *(const float4*)(lp + 4);
                xv[c*8+0] = x0.x; xv[c*8+1] = x0.y; xv[c*8+2] = x0.z; xv[c*8+3] = x0.w;
                xv[c*8+4] = x1.x; xv[c*8+5] = x1.y; xv[c*8+6] = x1.z; xv[c*8+7] = x1.w;
            }
            if (w == 0) {
                unsigned short* gp = Qb + (size_t)grow * 128 + rcol;
#pragma unroll
                for (int c = 0; c < 4; ++c) {
                    short8 r;
#pragma unroll
                    for (int j = 0; j < 8; ++j) r[j] = (short)f2bf(xv[c*8+j]);
                    *(short8*)(gp + c * 8) = r;
                }
            } else {
                // int8 per-head symmetric quantization (2 heads per thread)
#pragma unroll
                for (int g = 0; g < 2; ++g) {
                    const int b = g * 16;
                    float mx = 0.f;
#pragma unroll
                    for (int j = 0; j < 16; ++j) mx = fmaxf(mx, fabsf(xv[b + j]));
                    const float inv = (mx > 0.f) ? 127.0f / mx : 0.f;
                    unsigned int du[4];
#pragma unroll
                    for (int d = 0; d < 4; ++d) {
                        const int b0 = (int)rintf(xv[b + d*4 + 0] * inv);
                        const int b1 = (int)rintf(xv[b + d*4 + 1] * inv);
                        const int b2 = (int)rintf(xv[b + d*4 + 2] * inv);
                        const int b3 = (int)rintf(xv[b + d*4 + 3] * inv);
                        du[d] = (unsigned)(b0 & 255) | ((unsigned)(b1 & 255) << 8)
                              | ((unsigned)(b2 & 255) << 16) | ((unsigned)(b3 & 255) << 24);
                    }
                    const int h = h0 + g;
                    unsigned char* gp = KVb + (size_t)grow * 256 + ((w == 1) ? 0 : 128) + h * 16;
                    *(uint4*)gp = (uint4){du[0], du[1], du[2], du[3]};
                    // scales: K -> .x (folds 0.25), V -> .y
                    if (w == 1) scl[((size_t)grow * 8 + h) * 2 + 0] = mx * (1.0f / 508.0f);
                    else        scl[((size_t)grow * 8 + h) * 2 + 1] = mx * (1.0f / 127.0f);
                }
            }
        }
        __syncthreads();
    }
}

// ---------------------------------------------------------------------------
// Counting-sort pass 1 (standalone; packed word (bucket<<24|src<<8|dstlow),
// wave shfl_up scan). Verified in round 5.
// ---------------------------------------------------------------------------
__global__ __launch_bounds__(256) void bucket_pass1(
    const int* __restrict__ src, const int* __restrict__ dst,
    int* __restrict__ gcur, int* __restrict__ pbuf)
{
    __shared__ int hist[256];
    __shared__ int lofs[256];
    __shared__ int gbase[256];
    __shared__ int wsum[4];
    __shared__ int pktg[2048];

    const int t = threadIdx.x;
    hist[t] = 0;
    __syncthreads();

    const long long e0 = (long long)blockIdx.x * 2048 + t * 8;
    const bool valid = (e0 < NEDGES);
    unsigned int w8[8]; int b8[8], r8[8];
    if (valid) {
        const int4 sA = *(const int4*)(src + e0);
        const int4 sB = *(const int4*)(src + e0 + 4);
        const int4 dA = *(const int4*)(dst + e0);
        const int4 dB = *(const int4*)(dst + e0 + 4);
        const int dd[8] = {dA.x, dA.y, dA.z, dA.w, dB.x, dB.y, dB.z, dB.w};
        const int ss[8] = {sA.x, sA.y, sA.z, sA.w, sB.x, sB.y, sB.z, sB.w};
#pragma unroll
        for (int j = 0; j < 8; ++j) {
            const int bb = dd[j] >> 8;
            b8[j] = bb;
            w8[j] = ((unsigned)bb << 24) | ((unsigned)ss[j] << 8) | (unsigned)(dd[j] & 255);
            r8[j] = atomicAdd(&hist[bb], 1);
        }
    }
    __syncthreads();

    const int v = hist[t];
    if (t < NB && v > 0) gbase[t] = atomicAdd(&gcur[t], v);

    int x = v;
#pragma unroll
    for (int off = 1; off < 64; off <<= 1) {
        const int y = __shfl_up(x, off);
        if ((t & 63) >= off) x += y;
    }
    if ((t & 63) == 63) wsum[t >> 6] = x;
    __syncthreads();
    int pre = 0;
#pragma unroll
    for (int ww = 0; ww < 4; ++ww)
        if (ww < (t >> 6)) pre += wsum[ww];
    const int tot = wsum[0] + wsum[1] + wsum[2] + wsum[3];
    lofs[t] = x + pre - v;          // exclusive prefix
    __syncthreads();

    if (valid) {
#pragma unroll
        for (int j = 0; j < 8; ++j)
            pktg[lofs[b8[j]] + r8[j]] = (int)w8[j];
    }
    __syncthreads();

#pragma unroll
    for (int j = 0; j < 8; ++j) {
        const int slot = t + 256 * j;
        if (slot < tot) {
            const unsigned int w = (unsigned int)pktg[slot];
            const int bb = (int)(w >> 24);
            const long long g = (long long)bb * BCAP + gbase[bb] + (slot - lofs[bb]);
            pbuf[g] = (int)(w & 0x00FFFFFFu);
        }
    }
}

// ---------------------------------------------------------------------------
// Counting-sort pass 2: one block per bucket, 1024 threads, packed word,
// wave shfl_up scan. Verified in round 5.
// ---------------------------------------------------------------------------
__global__ __launch_bounds__(1024) void bucket_pass2(
    const int* __restrict__ pbuf, const int* __restrict__ gcur,
    int* __restrict__ eidx, int2* __restrict__ offs2)
{
    __shared__ int hist[256];
    __shared__ int cur[256];
    __shared__ int wsum[4];
    __shared__ int pstash[BCAP];    // 40 KB packed words
    __shared__ int srcbuf[BCAP];    // 40 KB grouped src ids

    const int b = blockIdx.x;
    const int t = threadIdx.x;
    int cnt = gcur[b];
    if (cnt > BCAP) cnt = BCAP;
    const long long base = (long long)b * BCAP;

    if (t < 256) hist[t] = 0;
    __syncthreads();

    for (int i = t; i < cnt; i += 1024) {
        const int g = pbuf[base + i];
        pstash[i] = g;
        atomicAdd(&hist[g & 255], 1);
    }
    __syncthreads();

    int x = 0, v = 0;
    if (t < 256) {
        v = hist[t];
        x = v;
#pragma unroll
        for (int off = 1; off < 64; off <<= 1) {
            const int y = __shfl_up(x, off);
            if ((t & 63) >= off) x += y;
        }
        if ((t & 63) == 63) wsum[t >> 6] = x;
    }
    __syncthreads();
    if (t < 256) {
        int pre = 0;
#pragma unroll
        for (int ww = 0; ww < 4; ++ww)
            if (ww < (t >> 6)) pre += wsum[ww];
        const int ex = x + pre - v;          // exclusive
        cur[t] = ex;
        const int n = b * 256 + t;
        if (n < NNODES) {
            int2 oe; oe.x = (int)(base + ex); oe.y = (int)(base + ex + v);
            offs2[n] = oe;
        }
    }
    __syncthreads();

    for (int i = t; i < cnt; i += 1024) {
        const int g = pstash[i];
        const int p = atomicAdd(&cur[g & 255], 1);
        srcbuf[p] = g >> 8;
    }
    __syncthreads();

    for (int i = t; i < cnt; i += 1024)
        eidx[base + i] = srcbuf[i];
}

// ---------------------------------------------------------------------------
// Aggregation: one wave per dst node; lane = (edge-slot eo=l>>3, head h=l&7).
// Round-6: KVb row is now 256B int8 (2 cache lines/edge, was 4) -- rounds
// 0-2 established the kernel is pinned by random-gather line traffic, so
// bytes/edge is THE lever. Per edge-lane: one uint4 K (16 int8), one uint4 V,
// one float2 scale (3.2MB array, L2-resident). kscale folds the 0.25 score
// scale; vscale folds into the weight before the V fma chain.
// ---------------------------------------------------------------------------
__global__ __launch_bounds__(256) void aggregate_kernel(
    const int* __restrict__ eidx, const int2* __restrict__ offs2,
    const unsigned short* __restrict__ Qb, const unsigned char* __restrict__ KVb,
    const float* __restrict__ scl, float* __restrict__ out)
{
    const int n = blockIdx.x * 4 + (threadIdx.x >> 6);
    const int l = threadIdx.x & 63;
    if (n >= NNODES) return;
    const int eo = l >> 3;       // edge slot 0..7
    const int h  = l & 7;        // head 0..7

    const unsigned short* qp = Qb + (size_t)n * 128 + h * 16;
    const uint4 qa = *(const uint4*)(qp);
    const uint4 qc = *(const uint4*)(qp + 8);
    float q[16];
    q[0]  = bflo(qa.x); q[1]  = bfhi(qa.x); q[2]  = bflo(qa.y); q[3]  = bfhi(qa.y);
    q[4]  = bflo(qa.z); q[5]  = bfhi(qa.z); q[6]  = bflo(qa.w); q[7]  = bfhi(qa.w);
    q[8]  = bflo(qc.x); q[9]  = bfhi(qc.x); q[10] = bflo(qc.y); q[11] = bfhi(qc.y);
    q[12] = bflo(qc.z); q[13] = bfhi(qc.z); q[14] = bflo(qc.w); q[15] = bfhi(qc.w);

    const int2 oe = offs2[n];
    const int beg = oe.x, end = oe.y;

    float acc[16];
#pragma unroll
    for (int j = 0; j < 16; ++j) acc[j] = 0.f;
    float zacc = 0.f;

    for (int i = beg; i < end; i += 16) {
        const int ei0 = i + eo;
        const int ei1 = ei0 + 8;
        const bool act0 = (ei0 < end);
        const bool act1 = (ei1 < end);
        const int s0 = eidx[act0 ? ei0 : beg];
        const int s1 = eidx[act1 ? ei1 : beg];

        const unsigned char* rp0 = KVb + (size_t)s0 * 256;
        const unsigned char* rp1 = KVb + (size_t)s1 * 256;
        const uint4 kw0 = *(const uint4*)(rp0 + h * 16);
        const uint4 vw0 = *(const uint4*)(rp0 + 128 + h * 16);
        const uint4 kw1 = *(const uint4*)(rp1 + h * 16);
        const uint4 vw1 = *(const uint4*)(rp1 + 128 + h * 16);
        const float2 sc0 = *(const float2*)(scl + ((size_t)s0 * 8 + h) * 2);
        const float2 sc1 = *(const float2*)(scl + ((size_t)s1 * 8 + h) * 2);

        float p0;
        p0 = sb2f(kw0.x, 0) * q[0];
        p0 = fmaf(sb2f(kw0.x, 1), q[1],  p0); p0 = fmaf(sb2f(kw0.x, 2), q[2],  p0);
        p0 = fmaf(sb2f(kw0.x, 3), q[3],  p0); p0 = fmaf(sb2f(kw0.y, 0), q[4],  p0);
        p0 = fmaf(sb2f(kw0.y, 1), q[5],  p0); p0 = fmaf(sb2f(kw0.y, 2), q[6],  p0);
        p0 = fmaf(sb2f(kw0.y, 3), q[7],  p0); p0 = fmaf(sb2f(kw0.z, 0), q[8],  p0);
        p0 = fmaf(sb2f(kw0.z, 1), q[9],  p0); p0 = fmaf(sb2f(kw0.z, 2), q[10], p0);
        p0 = fmaf(sb2f(kw0.z, 3), q[11], p0); p0 = fmaf(sb2f(kw0.w, 0), q[12], p0);
        p0 = fmaf(sb2f(kw0.w, 1), q[13], p0); p0 = fmaf(sb2f(kw0.w, 2), q[14], p0);
        p0 = fmaf(sb2f(kw0.w, 3), q[15], p0);
        p0 *= sc0.x;                      // kmax/(127*4): dequant + 1/sqrt(D)

        float p1;
        p1 = sb2f(kw1.x, 0) * q[0];
        p1 = fmaf(sb2f(kw1.x, 1), q[1],  p1); p1 = fmaf(sb2f(kw1.x, 2), q[2],  p1);
        p1 = fmaf(sb2f(kw1.x, 3), q[3],  p1); p1 = fmaf(sb2f(kw1.y, 0), q[4],  p1);
        p1 = fmaf(sb2f(kw1.y, 1), q[5],  p1); p1 = fmaf(sb2f(kw1.y, 2), q[6],  p1);
        p1 = fmaf(sb2f(kw1.y, 3), q[7],  p1); p1 = fmaf(sb2f(kw1.z, 0), q[8],  p1);
        p1 = fmaf(sb2f(kw1.z, 1), q[9],  p1); p1 = fmaf(sb2f(kw1.z, 2), q[10], p1);
        p1 = fmaf(sb2f(kw1.z, 3), q[11], p1); p1 = fmaf(sb2f(kw1.w, 0), q[12], p1);
        p1 = fmaf(sb2f(kw1.w, 1), q[13], p1); p1 = fmaf(sb2f(kw1.w, 2), q[14], p1);
        p1 = fmaf(sb2f(kw1.w, 3), q[15], p1);
        p1 *= sc1.x;

        float w0 = __expf(fminf(fmaxf(p0, -5.f), 5.f));
        float w1 = __expf(fminf(fmaxf(p1, -5.f), 5.f));
        w0 = act0 ? w0 : 0.f;
        w1 = act1 ? w1 : 0.f;
        zacc += w0 + w1;
        const float wv0 = w0 * sc0.y;     // fold vscale into the weight
        const float wv1 = w1 * sc1.y;

        acc[0]  = fmaf(sb2f(vw0.x, 0), wv0, acc[0]);  acc[1]  = fmaf(sb2f(vw0.x, 1), wv0, acc[1]);
        acc[2]  = fmaf(sb2f(vw0.x, 2), wv0, acc[2]);  acc[3]  = fmaf(sb2f(vw0.x, 3), wv0, acc[3]);
        acc[4]  = fmaf(sb2f(vw0.y, 0), wv0, acc[4]);  acc[5]  = fmaf(sb2f(vw0.y, 1), wv0, acc[5]);
        acc[6]  = fmaf(sb2f(vw0.y, 2), wv0, acc[6]);  acc[7]  = fmaf(sb2f(vw0.y, 3), wv0, acc[7]);
        acc[8]  = fmaf(sb2f(vw0.z, 0), wv0, acc[8]);  acc[9]  = fmaf(sb2f(vw0.z, 1), wv0, acc[9]);
        acc[10] = fmaf(sb2f(vw0.z, 2), wv0, acc[10]); acc[11] = fmaf(sb2f(vw0.z, 3), wv0, acc[11]);
        acc[12] = fmaf(sb2f(vw0.w, 0), wv0, acc[12]); acc[13] = fmaf(sb2f(vw0.w, 1), wv0, acc[13]);
        acc[14] = fmaf(sb2f(vw0.w, 2), wv0, acc[14]); acc[15] = fmaf(sb2f(vw0.w, 3), wv0, acc[15]);

        acc[0]  = fmaf(sb2f(vw1.x, 0), wv1, acc[0]);  acc[1]  = fmaf(sb2f(vw1.x, 1), wv1, acc[1]);
        acc[2]  = fmaf(sb2f(vw1.x, 2), wv1, acc[2]);  acc[3]  = fmaf(sb2f(vw1.x, 3), wv1, acc[3]);
        acc[4]  = fmaf(sb2f(vw1.y, 0), wv1, acc[4]);  acc[5]  = fmaf(sb2f(vw1.y, 1), wv1, acc[5]);
        acc[6]  = fmaf(sb2f(vw1.y, 2), wv1, acc[6]);  acc[7]  = fmaf(sb2f(vw1.y, 3), wv1, acc[7]);
        acc[8]  = fmaf(sb2f(vw1.z, 0), wv1, acc[8]);  acc[9]  = fmaf(sb2f(vw1.z, 1), wv1, acc[9]);
        acc[10] = fmaf(sb2f(vw1.z, 2), wv1, acc[10]); acc[11] = fmaf(sb2f(vw1.z, 3), wv1, acc[11]);
        acc[12] = fmaf(sb2f(vw1.w, 0), wv1, acc[12]); acc[13] = fmaf(sb2f(vw1.w, 1), wv1, acc[13]);
        acc[14] = fmaf(sb2f(vw1.w, 2), wv1, acc[14]); acc[15] = fmaf(sb2f(vw1.w, 3), wv1, acc[15]);
    }

    // reduce across edge slots (lanes differing in bits 3..5)
#pragma unroll
    for (int st = 8; st < 64; st <<= 1) {
        zacc += __shfl_xor(zacc, st);
#pragma unroll
        for (int j = 0; j < 16; ++j) acc[j] += __shfl_xor(acc[j], st);
    }

    if (eo == 0) {
        const float inv = 1.0f / zacc;
        float* op = out + (size_t)n * 128 + h * 16;
        *(float4*)(op)      = make_float4(acc[0]*inv,  acc[1]*inv,  acc[2]*inv,  acc[3]*inv);
        *(float4*)(op + 4)  = make_float4(acc[4]*inv,  acc[5]*inv,  acc[6]*inv,  acc[7]*inv);
        *(float4*)(op + 8)  = make_float4(acc[8]*inv,  acc[9]*inv,  acc[10]*inv, acc[11]*inv);
        *(float4*)(op + 12) = make_float4(acc[12]*inv, acc[13]*inv, acc[14]*inv, acc[15]*inv);
    }
}

extern "C" void kernel_launch(void* const* d_in, const int* in_sizes, int n_in,
                              void* d_out, int out_size, void* d_ws, size_t ws_size,
                              hipStream_t stream)
{
    const float* state = (const float*)d_in[0];
    const int*   src   = (const int*)d_in[1];
    const int*   dst   = (const int*)d_in[2];
    const float* WQ    = (const float*)d_in[3];
    const float* bQ    = (const float*)d_in[4];
    const float* WK    = (const float*)d_in[5];
    const float* bK    = (const float*)d_in[6];
    const float* WV    = (const float*)d_in[7];
    const float* bV    = (const float*)d_in[8];
    float* out = (float*)d_out;

    unsigned short* Qb  = (unsigned short*)d_ws;                        // 12.8 MB
    unsigned char*  KVb = (unsigned char*)(Qb + (size_t)NNODES * 128);  // 12.8 MB
    float*          scl = (float*)(KVb + (size_t)NNODES * 256);         // 3.2 MB
    unsigned short* WT  = (unsigned short*)(scl + (size_t)NNODES * 16); // 96 KB
    int* pbuf  = (int*)(WT + 3 * 16384);                                // NB*BCAP*4B
    int* eidx  = pbuf + (size_t)NB * BCAP;
    int* gcur  = eidx + (size_t)NB * BCAP;                              // 256
    int2* offs2 = (int2*)(gcur + 256);                                  // 50000 int2

    cast_wt<<<3 * 128, 128, 0, stream>>>(WQ, WK, WV, WT, gcur);
    proj_mfma<<<(NNODES + 63) / 64, 256, 0, stream>>>(state, WT, bQ, bK, bV, Qb, KVb, scl);

    bucket_pass1<<<(NEDGES + 2047) / 2048, 256, 0, stream>>>(src, dst, gcur, pbuf);
    bucket_pass2<<<NB, 1024, 0, stream>>>(pbuf, gcur, eidx, offs2);

    aggregate_kernel<<<(NNODES + 3) / 4, 256, 0, stream>>>(eidx, offs2, Qb, KVb, scl, out);
}